// Round 1
// 130.184 us; speedup vs baseline: 1.0068x; 1.0068x over previous
//
#include <hip/hip_runtime.h>
#include <hip/hip_bf16.h>
#include <hip/hip_fp16.h>
#include <stdint.h>

// out[e] = sum_d |nodes[r[e]][d] - nodes[c[e]][d]| * w[d] + b[0]
// E = 600000, D = 128, N_OUT = 1.
//
// R1: fp32 gather, FETCH 287 MB, 85 us (traffic-bound).
// R2: fp16 table in ws (convert ~13 us), FETCH 132 MB, gather 42.4 us,
//     VALUBusy 41% -> mixed latency/VALU regime.
// R3: 8 lanes/edge, 4 loads/thread -> neutral (131 us total). VALU work per
//     gathered byte unchanged, so neither pipe freed.
// R4 (this): packed-fp16 math. |a-b| via v_pk_sub_f16 + and-mask, then
//     v_dot2_f32_f16 (fdot2) -> ~2.7x fewer VALU ops per chunk. Freed VGPRs
//     spent on MLP: 4 lanes/edge, 8 independent 16B gathers/thread.
//     w pre-converted to fp16 in the convert pass (appended to table).

#define D_FEAT 128

typedef _Float16 h2v __attribute__((ext_vector_type(2)));

// ---- pass 1: fp32 -> fp16 table conversion (streaming) + w conversion ----
__global__ __launch_bounds__(256) void convert_f32_to_f16(
    const float* __restrict__ src, __half* __restrict__ dst,
    const float* __restrict__ w, __half* __restrict__ wh, int n8)
{
    const int i = blockIdx.x * blockDim.x + threadIdx.x;

    // 16 threads of block 0 additionally convert w (128 floats -> 128 halves)
    if (blockIdx.x == 0 && threadIdx.x < (D_FEAT / 8)) {
        const float4* s = (const float4*)w + 2 * (size_t)threadIdx.x;
        const float4 a = s[0];
        const float4 c = s[1];
        float4 packed;
        ((__half2*)&packed)[0] = __floats2half2_rn(a.x, a.y);
        ((__half2*)&packed)[1] = __floats2half2_rn(a.z, a.w);
        ((__half2*)&packed)[2] = __floats2half2_rn(c.x, c.y);
        ((__half2*)&packed)[3] = __floats2half2_rn(c.z, c.w);
        ((float4*)wh)[threadIdx.x] = packed;
    }

    if (i >= n8) return;
    const float4* s = (const float4*)src + 2 * (size_t)i;
    const float4 a = s[0];
    const float4 c = s[1];
    float4 packed;
    ((__half2*)&packed)[0] = __floats2half2_rn(a.x, a.y);
    ((__half2*)&packed)[1] = __floats2half2_rn(a.z, a.w);
    ((__half2*)&packed)[2] = __floats2half2_rn(c.x, c.y);
    ((__half2*)&packed)[3] = __floats2half2_rn(c.z, c.w);
    ((float4*)dst)[i] = packed;  // 16 B = 8 halves
}

// ---- packed abs-diff dot: acc += dot(|a-b|, w) over 2 halves ----
__device__ __forceinline__ float absdot(uint32_t a, uint32_t b, uint32_t w,
                                        float acc)
{
#if __has_builtin(__builtin_amdgcn_fdot2)
    const h2v av = __builtin_bit_cast(h2v, a);
    const h2v bv = __builtin_bit_cast(h2v, b);
    const h2v d  = av - bv;                                   // v_pk_sub_f16
    const uint32_t ad = __builtin_bit_cast(uint32_t, d) & 0x7FFF7FFFu;
    return __builtin_amdgcn_fdot2(__builtin_bit_cast(h2v, ad),
                                  __builtin_bit_cast(h2v, w), acc, false);
#else
    const float2 x = __half22float2(__builtin_bit_cast(__half2, a));
    const float2 y = __half22float2(__builtin_bit_cast(__half2, b));
    const float2 ww = __half22float2(__builtin_bit_cast(__half2, w));
    return acc + fabsf(x.x - y.x) * ww.x + fabsf(x.y - y.y) * ww.y;
#endif
}

// ---- pass 2: edge gather, 4 lanes/edge, 8 row-loads in flight/thread ----
// Row = 128 halves = 16 chunks of 16B. Lane l (0..3) loads chunks
// {l, l+4, l+8, l+12} of each row: lanes 0-3 cover a contiguous 64B sector
// per load instruction (16 edges/wave -> 16 x 64B sectors per instr).
__global__ __launch_bounds__(256) void gather_edges_f16_dot(
    const __half* __restrict__ tbl,
    const __half* __restrict__ wh,
    const int*   __restrict__ r_idx,
    const int*   __restrict__ c_idx,
    const float* __restrict__ b,
    float*       __restrict__ out,
    int n_edges)
{
    const int tid  = blockIdx.x * blockDim.x + threadIdx.x;
    const int lane = tid & 3;
    const int edge = tid >> 2;
    if (edge >= n_edges) return;

    const int r = r_idx[edge];
    const int c = c_idx[edge];

    const uint4* arow = (const uint4*)(tbl + (size_t)r * D_FEAT);
    const uint4* brow = (const uint4*)(tbl + (size_t)c * D_FEAT);

    // 8 independent gather loads issued back-to-back:
    const uint4 a0 = arow[lane];
    const uint4 a1 = arow[lane + 4];
    const uint4 a2 = arow[lane + 8];
    const uint4 a3 = arow[lane + 12];
    const uint4 b0 = brow[lane];
    const uint4 b1 = brow[lane + 4];
    const uint4 b2 = brow[lane + 8];
    const uint4 b3 = brow[lane + 12];

    // w (fp16, 256 B) is L1-resident.
    const uint4* wv = (const uint4*)wh;
    const uint4 w0 = wv[lane];
    const uint4 w1 = wv[lane + 4];
    const uint4 w2 = wv[lane + 8];
    const uint4 w3 = wv[lane + 12];

    // 4 independent accumulator chains of 4 fdot2 each.
    float s0 = 0.f, s1 = 0.f, s2 = 0.f, s3 = 0.f;
    s0 = absdot(a0.x, b0.x, w0.x, s0);
    s0 = absdot(a0.y, b0.y, w0.y, s0);
    s0 = absdot(a0.z, b0.z, w0.z, s0);
    s0 = absdot(a0.w, b0.w, w0.w, s0);

    s1 = absdot(a1.x, b1.x, w1.x, s1);
    s1 = absdot(a1.y, b1.y, w1.y, s1);
    s1 = absdot(a1.z, b1.z, w1.z, s1);
    s1 = absdot(a1.w, b1.w, w1.w, s1);

    s2 = absdot(a2.x, b2.x, w2.x, s2);
    s2 = absdot(a2.y, b2.y, w2.y, s2);
    s2 = absdot(a2.z, b2.z, w2.z, s2);
    s2 = absdot(a2.w, b2.w, w2.w, s2);

    s3 = absdot(a3.x, b3.x, w3.x, s3);
    s3 = absdot(a3.y, b3.y, w3.y, s3);
    s3 = absdot(a3.z, b3.z, w3.z, s3);
    s3 = absdot(a3.w, b3.w, w3.w, s3);

    float s = (s0 + s1) + (s2 + s3);

    // Reduce across the 4-lane group (xor masks < 4 never cross groups).
    s += __shfl_xor(s, 2, 64);
    s += __shfl_xor(s, 1, 64);

    if (lane == 0)
        out[edge] = s + b[0];
}

// ---- fallback: direct fp32 gather (R1 path), if ws too small ----
__global__ __launch_bounds__(256) void gather_edges_f32(
    const float* __restrict__ nodes,
    const int*   __restrict__ r_idx,
    const int*   __restrict__ c_idx,
    const float* __restrict__ w,
    const float* __restrict__ b,
    float*       __restrict__ out,
    int n_edges)
{
    const int tid  = blockIdx.x * blockDim.x + threadIdx.x;
    const int lane = tid & 31;
    const int edge = tid >> 5;
    if (edge >= n_edges) return;

    const int r = r_idx[edge];
    const int c = c_idx[edge];

    const float4 wv = ((const float4*)w)[lane];
    const float4 av = ((const float4*)(nodes + (size_t)r * D_FEAT))[lane];
    const float4 bv = ((const float4*)(nodes + (size_t)c * D_FEAT))[lane];

    float s = fabsf(av.x - bv.x) * wv.x
            + fabsf(av.y - bv.y) * wv.y
            + fabsf(av.z - bv.z) * wv.z
            + fabsf(av.w - bv.w) * wv.w;

    #pragma unroll
    for (int off = 16; off > 0; off >>= 1)
        s += __shfl_xor(s, off, 64);

    if (lane == 0)
        out[edge] = s + b[0];
}

extern "C" void kernel_launch(void* const* d_in, const int* in_sizes, int n_in,
                              void* d_out, int out_size, void* d_ws, size_t ws_size,
                              hipStream_t stream) {
    const float* nodes = (const float*)d_in[0];   // [N_NODES, 128] f32
    const int*   r_idx = (const int*)d_in[1];     // [E] int
    const int*   c_idx = (const int*)d_in[2];     // [E] int
    const float* w     = (const float*)d_in[3];   // [128, 1] f32
    const float* b     = (const float*)d_in[4];   // [1] f32
    float*       out   = (float*)d_out;           // [E] f32

    const int n_edges   = in_sizes[1];
    const int n_nodes_f = in_sizes[0];            // n_nodes * 128 floats
    const size_t tbl_bytes = (size_t)n_nodes_f * sizeof(__half);
    const size_t wh_bytes  = (size_t)D_FEAT * sizeof(__half);

    if (ws_size >= tbl_bytes + wh_bytes && (n_nodes_f & 7) == 0) {
        __half* tbl = (__half*)d_ws;
        __half* wh  = tbl + (size_t)n_nodes_f;    // 128 halves appended

        const int n8 = n_nodes_f / 8;
        const int cblock = 256;
        const int cgrid  = (n8 + cblock - 1) / cblock;
        convert_f32_to_f16<<<cgrid, cblock, 0, stream>>>(nodes, tbl, w, wh, n8);

        // 4 threads/edge, 256-thread blocks -> 64 edges/block
        const int block = 256;
        const int grid  = (int)(((long long)n_edges * 4 + block - 1) / block);
        gather_edges_f16_dot<<<grid, block, 0, stream>>>(
            tbl, wh, r_idx, c_idx, b, out, n_edges);
    } else {
        const int block = 256;
        const int grid  = (int)(((long long)n_edges * 32 + block - 1) / block);
        gather_edges_f32<<<grid, block, 0, stream>>>(
            nodes, r_idx, c_idx, w, b, out, n_edges);
    }
}